// Round 6
// baseline (3920.406 us; speedup 1.0000x reference)
//
#include <hip/hip_runtime.h>
#include <math.h>

#define BATCH 64
#define TLEN 512
#define EMB 256
#define HID 256          // per-direction hidden
#define G4 1024          // 4*HID
#define KTAG 12
#define START_TAG 10
#define STOP_TAG 11
#define NEGV -10000.0f
#define SENT 0xFFFFFFFFu // -NaN sentinel: tanh-bounded h can never be this

#define LOG2E 1.4426950408889634f

typedef float f4 __attribute__((ext_vector_type(4)));

__device__ __forceinline__ float fsig(float x) {
    return __builtin_amdgcn_rcpf(1.f + __builtin_amdgcn_exp2f(-LOG2E * x));
}
__device__ __forceinline__ float ftanh(float x) {
    return 1.f - 2.f * __builtin_amdgcn_rcpf(1.f + __builtin_amdgcn_exp2f(2.f * LOG2E * x));
}
__device__ __forceinline__ void st_llc(float* p, float v) {
    __hip_atomic_store(p, v, __ATOMIC_RELAXED, __HIP_MEMORY_SCOPE_AGENT);
}
__device__ __forceinline__ unsigned ld_llc_u(const unsigned* p) {
    return __hip_atomic_load(p, __ATOMIC_RELAXED, __HIP_MEMORY_SCOPE_AGENT);
}

// ---------------------------------------------------------------------------
// K1: fused embedding gather + input projection, both directions.
// x layout: x[r][gate*256+j], r = b*512+t. float4 epilogue stores.
// ---------------------------------------------------------------------------
#define MT 128
#define NT 128
#define KC 32
#define LDP 132

__global__ __launch_bounds__(256) void proj_kernel(
    const int* __restrict__ sentence, const float* __restrict__ emb,
    const float* __restrict__ Wf_ih, const float* __restrict__ Wb_ih,
    const float* __restrict__ bf_ih, const float* __restrict__ bf_hh,
    const float* __restrict__ bb_ih, const float* __restrict__ bb_hh,
    float* __restrict__ xf, float* __restrict__ xb) {
    int mtile = blockIdx.x;
    int ntile = blockIdx.y;
    int tid = threadIdx.x;

    __shared__ float As[KC][LDP];
    __shared__ float Bs[KC][LDP];
    __shared__ int tok[MT];

    int g2base = ntile * NT;
    const bool fwd = (g2base < 1024);
    const float* Wih = fwd ? Wf_ih : Wb_ih;
    const float* bia = fwd ? bf_ih : bb_ih;
    const float* bib = fwd ? bf_hh : bb_hh;
    float* dst       = fwd ? xf    : xb;
    int glb = g2base & 1023;

    if (tid < MT) tok[tid] = sentence[(size_t)mtile * MT + tid];
    __syncthreads();

    float acc[8][8];
#pragma unroll
    for (int i = 0; i < 8; ++i)
#pragma unroll
        for (int jj = 0; jj < 8; ++jj) acc[i][jj] = 0.f;

    int m0 = (tid & 15) * 8;
    int n0 = (tid >> 4) * 8;
    int lr = tid >> 3;
    int lk = (tid & 7) * 4;

    for (int k0 = 0; k0 < EMB; k0 += KC) {
#pragma unroll
        for (int i = 0; i < 4; ++i) {
            int r = lr + 32 * i;
            float4 v = *(const float4*)(emb + (size_t)tok[r] * EMB + k0 + lk);
            As[lk + 0][r] = v.x; As[lk + 1][r] = v.y;
            As[lk + 2][r] = v.z; As[lk + 3][r] = v.w;
            float4 w = *(const float4*)(Wih + (size_t)(glb + r) * EMB + k0 + lk);
            Bs[lk + 0][r] = w.x; Bs[lk + 1][r] = w.y;
            Bs[lk + 2][r] = w.z; Bs[lk + 3][r] = w.w;
        }
        __syncthreads();
#pragma unroll
        for (int kk = 0; kk < KC; ++kk) {
            float4 a0 = *(const float4*)&As[kk][m0];
            float4 a1 = *(const float4*)&As[kk][m0 + 4];
            float4 b0 = *(const float4*)&Bs[kk][n0];
            float4 b1 = *(const float4*)&Bs[kk][n0 + 4];
            float av[8] = {a0.x, a0.y, a0.z, a0.w, a1.x, a1.y, a1.z, a1.w};
            float bv[8] = {b0.x, b0.y, b0.z, b0.w, b1.x, b1.y, b1.z, b1.w};
#pragma unroll
            for (int i = 0; i < 8; ++i)
#pragma unroll
                for (int jj = 0; jj < 8; ++jj) acc[i][jj] += av[i] * bv[jj];
        }
        __syncthreads();
    }

    float bs[8];
#pragma unroll
    for (int jj = 0; jj < 8; ++jj) {
        int gl = glb + n0 + jj;
        bs[jj] = bia[gl] + bib[gl];
    }
#pragma unroll
    for (int i = 0; i < 8; ++i) {
        size_t r = (size_t)mtile * MT + m0 + i;
        float4 s0 = {acc[i][0] + bs[0], acc[i][1] + bs[1],
                     acc[i][2] + bs[2], acc[i][3] + bs[3]};
        float4 s1 = {acc[i][4] + bs[4], acc[i][5] + bs[5],
                     acc[i][6] + bs[6], acc[i][7] + bs[7]};
        *(float4*)(dst + r * (size_t)G4 + glb + n0)     = s0;
        *(float4*)(dst + r * (size_t)G4 + glb + n0 + 4) = s1;
    }
}

// ---------------------------------------------------------------------------
// K2: cooperative LSTM scan v11 — fully wave-autonomous exchange.
// Measured ladder: v5 1778us (2 barriers, L2-W) -> v8 2008us (LDS-W, proves
// W-BW was NOT the bottleneck) -> v10 1690us (1 barrier + x-prefetch).
// Residual ~2us/step = barrier coupling: all 4 waves rendezvous each step,
// so step time = max over waves of (LLC poll discovery), and skew compounds
// over the 512-step chain.
// v11 removes ALL in-loop barriers:
//   * Wl (128 KiB) was ALWAYS thread-private ([tid]-indexed only) -> never
//     needed a barrier.
//   * hsL becomes WAVE-private: each wave polls its own copy of the h it
//     consumes (lane polls h[bb][lane*4..+3] for 4 batches = 16 agent-scope
//     dwords, one LLC round-trip; 4x redundancy = 4MB/step chip-wide, cheap)
//     and stages into its own 4.6 KiB LDS region. Cross-lane write->read
//     within the wave is ordered by compiler alias analysis (same hsL
//     object, runtime offsets -> lgkmcnt inserted) + wave_barrier builtin
//     as a scheduling fence.
//   * Each wave's 512-step chain self-times: poll -> stage -> compute ->
//     publish. No rendezvous, no vmcnt drain, no skew amplification.
// Compute/reduce/publish identical to v10 -> identical arithmetic.
// No inline asm (v7/v9 lesson); builtins only.
// ---------------------------------------------------------------------------
__global__ __launch_bounds__(256, 1) void lstm_scan11(
    const float* __restrict__ xf, const float* __restrict__ xb,
    const float* __restrict__ Wf_hh, const float* __restrict__ Wb_hh,
    float* __restrict__ hcat) {
    int blk = blockIdx.x;
    int grp = blk & 31;          // members of a group share blk%8 (XCD heur.)
    int s   = blk >> 5;          // J-slice 0..7
    int d   = grp >> 4;          // direction
    int gq  = grp & 15;          // batch quartet
    int b0  = gq * 4;
    int tid = threadIdx.x;
    int kseg = tid & 7;
    int j    = tid >> 3;
    int J    = s * 32 + j;
    int bown = kseg & 3;
    int wv   = tid >> 6;         // wave id 0..3
    int lane = tid & 63;

    __shared__ f4 Wl[4][8][256];       // 128 KiB: per-thread private W slices
    __shared__ float hsL[4 * 1152];    // 18 KiB: per-WAVE h stage [wv][bb][288]

    // --- stage W (thread-private slots; no barrier needed, ever) ---
    const float* Whh = d ? Wb_hh : Wf_hh;
#pragma unroll
    for (int g = 0; g < 4; ++g)
#pragma unroll
        for (int q = 0; q < 8; ++q)
            Wl[g][q][tid] =
                *(const f4*)(Whh + (size_t)(g * 256 + J) * 256 + kseg * 32 + q * 4);

    // --- register-stage q=0..3 from own LDS slot (no-lose; see v10 note) ---
    f4 Wreg[4][4];
#pragma unroll
    for (int g = 0; g < 4; ++g)
#pragma unroll
        for (int q = 0; q < 4; ++q)
            Wreg[g][q] = Wl[g][q][tid];

    const float* x = d ? xb : xf;
    const float* xrow0 = x + (size_t)(b0 + bown) * TLEN * G4 + J;

    float* hsW = hsL + wv * 1152;               // this wave's region
    int wsw = (lane >> 3) * 36 + (lane & 7) * 4; // stage slot for lane's f4
    float c = 0.f;

    // prologue: x for the first step
    const float* xr0 = xrow0 + (size_t)(d ? (TLEN - 1) : 0) * G4;
    float xc0 = xr0[0], xc1 = xr0[256], xc2 = xr0[512], xc3 = xr0[768];

    for (int i = 0; i < TLEN; ++i) {
        int t = d ? (TLEN - 1 - i) : i;

        if (i == 0) {
            f4 z = {0.f, 0.f, 0.f, 0.f};
#pragma unroll
            for (int bb = 0; bb < 4; ++bb)
                *(f4*)(hsW + bb * 288 + wsw) = z;
        } else {
            int tp = d ? (t + 1) : (t - 1);
            // lane polls positions lane*4..+3 of all 4 batches (16 dwords,
            // independent loads -> single LLC round-trip per retry)
            const unsigned* base = (const unsigned*)hcat +
                ((size_t)tp * BATCH + b0) * 512 + (size_t)d * HID + lane * 4;
            unsigned u[16];
            for (;;) {
#pragma unroll
                for (int bb = 0; bb < 4; ++bb) {
#pragma unroll
                    for (int e = 0; e < 4; ++e)
                        u[bb * 4 + e] = ld_llc_u(base + bb * 512 + e);
                }
                bool ok = true;
#pragma unroll
                for (int k = 0; k < 16; ++k) ok &= (u[k] != SENT);
                if (ok) break;
                __builtin_amdgcn_s_sleep(1);
            }
#pragma unroll
            for (int bb = 0; bb < 4; ++bb) {
                f4 hv = {__uint_as_float(u[bb * 4 + 0]),
                         __uint_as_float(u[bb * 4 + 1]),
                         __uint_as_float(u[bb * 4 + 2]),
                         __uint_as_float(u[bb * 4 + 3])};
                *(f4*)(hsW + bb * 288 + wsw) = hv;
            }
        }
        __builtin_amdgcn_wave_barrier();  // order stage writes before reads

        // --- prefetch x for the NEXT step (consumed a full step later) ---
        int tn = (i == TLEN - 1) ? t : (d ? (t - 1) : (t + 1));
        const float* xrn = xrow0 + (size_t)tn * G4;
        float xn0 = xrn[0], xn1 = xrn[256], xn2 = xrn[512], xn3 = xrn[768];

        // --- q-outer: read each W f4 once, reuse across 4 batches ---
        float a[4][4];               // [gate][bb], fully unrolled
#pragma unroll
        for (int g = 0; g < 4; ++g)
#pragma unroll
            for (int bb = 0; bb < 4; ++bb) a[g][bb] = 0.f;

        const float* hbase = hsW + kseg * 36;
#pragma unroll
        for (int q = 0; q < 8; ++q) {
            f4 w0, w1, w2, w3;
            if (q < 4) {
                w0 = Wreg[0][q]; w1 = Wreg[1][q];
                w2 = Wreg[2][q]; w3 = Wreg[3][q];
            } else {
                w0 = Wl[0][q][tid]; w1 = Wl[1][q][tid];
                w2 = Wl[2][q][tid]; w3 = Wl[3][q][tid];
            }
#pragma unroll
            for (int bb = 0; bb < 4; ++bb) {
                f4 h4 = *(const f4*)(hbase + bb * 288 + q * 4);
                a[0][bb] += w0.x*h4.x + w0.y*h4.y + w0.z*h4.z + w0.w*h4.w;
                a[1][bb] += w1.x*h4.x + w1.y*h4.y + w1.z*h4.z + w1.w*h4.w;
                a[2][bb] += w2.x*h4.x + w2.y*h4.y + w2.z*h4.z + w2.w*h4.w;
                a[3][bb] += w3.x*h4.x + w3.y*h4.y + w3.z*h4.z + w3.w*h4.w;
            }
        }

        // --- reduce over the 8-lane kseg group (lane bits 0..2) ---
#pragma unroll
        for (int bb = 0; bb < 4; ++bb)
#pragma unroll
            for (int m = 1; m <= 4; m <<= 1) {
                a[0][bb] += __shfl_xor(a[0][bb], m);
                a[1][bb] += __shfl_xor(a[1][bb], m);
                a[2][bb] += __shfl_xor(a[2][bb], m);
                a[3][bb] += __shfl_xor(a[3][bb], m);
            }

        // --- select own batch (constant-index ternary chain, no scratch) ---
        float A0 = bown == 0 ? a[0][0] : bown == 1 ? a[0][1] : bown == 2 ? a[0][2] : a[0][3];
        float A1 = bown == 0 ? a[1][0] : bown == 1 ? a[1][1] : bown == 2 ? a[1][2] : a[1][3];
        float A2 = bown == 0 ? a[2][0] : bown == 1 ? a[2][1] : bown == 2 ? a[2][2] : a[2][3];
        float A3 = bown == 0 ? a[3][0] : bown == 1 ? a[3][1] : bown == 2 ? a[3][2] : a[3][3];

        float ig = fsig(A0 + xc0);
        float fg = fsig(A1 + xc1);
        float gg = ftanh(A2 + xc2);
        float og = fsig(A3 + xc3);
        c = fg * c + ig * gg;
        float h = og * ftanh(c);
        if (kseg < 4)
            st_llc(hcat + ((size_t)t * BATCH + b0 + bown) * 512
                        + (size_t)d * HID + J, h);

        xc0 = xn0; xc1 = xn1; xc2 = xn2; xc3 = xn3;
        // no barriers: hsW is wave-private; next step's stage writes are
        // ordered after this step's reads by the wave's own program order.
    }
}

// ---------------------------------------------------------------------------
// K3: feats[t,b,k] = hcat[t,b,:] . W_out[k,:] + b_out[k].
// ---------------------------------------------------------------------------
__global__ __launch_bounds__(256) void feats_kernel(
    const float* __restrict__ hcat, const float* __restrict__ Wout,
    const float* __restrict__ bout, float* __restrict__ feats) {
    int wid = threadIdx.x >> 6;
    int lane = threadIdx.x & 63;
    size_t row = (size_t)blockIdx.x * 4 + wid;
    const float* hrow = hcat + row * 512;
    float4 h0 = *(const float4*)(hrow + lane * 8);
    float4 h1 = *(const float4*)(hrow + lane * 8 + 4);
    for (int k2 = 0; k2 < KTAG; ++k2) {
        const float* wr = Wout + (size_t)k2 * 512 + lane * 8;
        float4 w0 = *(const float4*)wr;
        float4 w1 = *(const float4*)(wr + 4);
        float p = h0.x * w0.x + h0.y * w0.y + h0.z * w0.z + h0.w * w0.w
                + h1.x * w1.x + h1.y * w1.y + h1.z * w1.z + h1.w * w1.w;
#pragma unroll
        for (int off = 32; off; off >>= 1) p += __shfl_down(p, off);
        if (lane == 0) feats[row * KTAG + k2] = p + bout[k2];
    }
}

// ---------------------------------------------------------------------------
// K4: Viterbi DP + backtrace. One wave per batch. 8-step feats prefetch ring.
// ---------------------------------------------------------------------------
__global__ __launch_bounds__(64) void viterbi_kernel(
    const float* __restrict__ feats, const float* __restrict__ trans,
    const int* __restrict__ slen, float* __restrict__ out) {
    int b = blockIdx.x;
    int lane = threadIdx.x;
    __shared__ unsigned char bp[TLEN][KTAG];

    int len = slen[b];
    float tr[KTAG];
#pragma unroll
    for (int p = 0; p < KTAG; ++p) tr[p] = 0.f;
    if (lane < KTAG) {
#pragma unroll
        for (int p = 0; p < KTAG; ++p) tr[p] = trans[lane * KTAG + p];
    }
    float tstop = (lane < KTAG) ? trans[STOP_TAG * KTAG + lane] : NEGV;
    float dp = (lane == START_TAG) ? 0.f : NEGV;

    float fb[8];
#pragma unroll
    for (int k = 0; k < 8; ++k)
        fb[k] = (lane < KTAG) ? feats[((size_t)k * BATCH + b) * KTAG + lane] : 0.f;

    for (int t0 = 0; t0 < TLEN; t0 += 8) {
#pragma unroll
        for (int u = 0; u < 8; ++u) {
            int t = t0 + u;
            float ftc = fb[u];
            int tn = t + 8;
            fb[u] = (tn < TLEN && lane < KTAG)
                        ? feats[((size_t)tn * BATCH + b) * KTAG + lane] : 0.f;
            float best = -1e30f;
            int arg = 0;
#pragma unroll
            for (int p = 0; p < KTAG; ++p) {
                float dpp = __shfl(dp, p);
                float sc = dpp + tr[p];
                if (sc > best) { best = sc; arg = p; }
            }
            bool m = (t < len);
            if (lane < KTAG) {
                dp = m ? (best + ftc) : dp;
                bp[t][lane] = (unsigned char)(m ? arg : lane);
            }
        }
    }

    float term = dp + tstop;
    float bbest = -1e30f;
    int barg = 0;
#pragma unroll
    for (int p = 0; p < KTAG; ++p) {
        float v = __shfl(term, p);
        if (v > bbest) { bbest = v; barg = p; }
    }
    if (lane == 0) {
        out[b] = bbest;
        float* path = out + BATCH + (size_t)b * TLEN;
        int tag = barg;
        for (int t = TLEN - 1; t >= 0; --t) {
            path[t] = (float)tag;
            tag = bp[t][tag];
        }
    }
}

// ---------------------------------------------------------------------------
extern "C" void kernel_launch(void* const* d_in, const int* in_sizes, int n_in,
                              void* d_out, int out_size, void* d_ws, size_t ws_size,
                              hipStream_t stream) {
    const int*   sentence = (const int*)d_in[0];
    const int*   slen     = (const int*)d_in[1];
    const float* emb      = (const float*)d_in[2];
    const float* Wf_ih    = (const float*)d_in[3];
    const float* Wf_hh    = (const float*)d_in[4];
    const float* bf_ih    = (const float*)d_in[5];
    const float* bf_hh    = (const float*)d_in[6];
    const float* Wb_ih    = (const float*)d_in[7];
    const float* Wb_hh    = (const float*)d_in[8];
    const float* bb_ih    = (const float*)d_in[9];
    const float* bb_hh    = (const float*)d_in[10];
    const float* W_out    = (const float*)d_in[11];
    const float* b_out    = (const float*)d_in[12];
    const float* trans    = (const float*)d_in[13];
    float* out = (float*)d_out;

    char* ws = (char*)d_ws;
    float* xf    = (float*)(ws);                       // 134,217,728 B
    float* xb    = (float*)(ws + 134217728ull);        // 134,217,728 B
    float* hcat  = (float*)(ws + 268435456ull);        //  67,108,864 B
    float* feats = (float*)(ws + 335544320ull);        //   1,572,864 B

    // sentinel-fill hcat: 0xFFFFFFFF = -NaN, unreachable for tanh-bounded h
    hipMemsetAsync(hcat, 0xFF, 67108864ull, stream);
    hipLaunchKernelGGL(proj_kernel, dim3(256, 16), dim3(256), 0, stream,
                       sentence, emb, Wf_ih, Wb_ih, bf_ih, bf_hh, bb_ih, bb_hh, xf, xb);
    hipLaunchKernelGGL(lstm_scan11, dim3(256), dim3(256), 0, stream,
                       xf, xb, Wf_hh, Wb_hh, hcat);
    hipLaunchKernelGGL(feats_kernel, dim3(8192), dim3(256), 0, stream,
                       hcat, W_out, b_out, feats);
    hipLaunchKernelGGL(viterbi_kernel, dim3(64), dim3(64), 0, stream,
                       feats, trans, slen, out);
}

// Round 7
// 2040.409 us; speedup vs baseline: 1.9214x; 1.9214x over previous
//
#include <hip/hip_runtime.h>
#include <math.h>

#define BATCH 64
#define TLEN 512
#define EMB 256
#define HID 256          // per-direction hidden
#define G4 1024          // 4*HID
#define KTAG 12
#define START_TAG 10
#define STOP_TAG 11
#define NEGV -10000.0f
#define SENT 0xFFFFFFFFu // -NaN sentinel: tanh-bounded h can never be this

#define LOG2E 1.4426950408889634f

typedef float f4 __attribute__((ext_vector_type(4)));

__device__ __forceinline__ float fsig(float x) {
    return __builtin_amdgcn_rcpf(1.f + __builtin_amdgcn_exp2f(-LOG2E * x));
}
__device__ __forceinline__ float ftanh(float x) {
    return 1.f - 2.f * __builtin_amdgcn_rcpf(1.f + __builtin_amdgcn_exp2f(2.f * LOG2E * x));
}
__device__ __forceinline__ void st_llc(float* p, float v) {
    __hip_atomic_store(p, v, __ATOMIC_RELAXED, __HIP_MEMORY_SCOPE_AGENT);
}
__device__ __forceinline__ unsigned ld_llc_u(const unsigned* p) {
    return __hip_atomic_load(p, __ATOMIC_RELAXED, __HIP_MEMORY_SCOPE_AGENT);
}
// 8-lane-group sum via DPP on the VALU pipe (replaces ds_swizzle shfl_xor,
// which serializes on the per-CU LDS pipe shared by all 4 waves).
// Steps: xor1 (quad_perm [1,0,3,2]=0xB1), xor2 (quad_perm [2,3,0,1]=0x4E),
// then row_half_mirror (0x141, lane i<->i^7 within 8). After xor1+xor2 the
// value is quad-uniform, so i^7 delivers the same value as i^4 ->
// BIT-IDENTICAL to the shfl_xor(1,2,4) reduction.
__device__ __forceinline__ float red8(float a) {
    float t;
    t = __int_as_float(__builtin_amdgcn_update_dpp(
            0, __float_as_int(a), 0xB1, 0xF, 0xF, true));
    a += t;
    t = __int_as_float(__builtin_amdgcn_update_dpp(
            0, __float_as_int(a), 0x4E, 0xF, 0xF, true));
    a += t;
    t = __int_as_float(__builtin_amdgcn_update_dpp(
            0, __float_as_int(a), 0x141, 0xF, 0xF, true));
    a += t;
    return a;
}

// ---------------------------------------------------------------------------
// K1: fused embedding gather + input projection, both directions.
// x layout: x[r][gate*256+j], r = b*512+t. float4 epilogue stores.
// ---------------------------------------------------------------------------
#define MT 128
#define NT 128
#define KC 32
#define LDP 132

__global__ __launch_bounds__(256) void proj_kernel(
    const int* __restrict__ sentence, const float* __restrict__ emb,
    const float* __restrict__ Wf_ih, const float* __restrict__ Wb_ih,
    const float* __restrict__ bf_ih, const float* __restrict__ bf_hh,
    const float* __restrict__ bb_ih, const float* __restrict__ bb_hh,
    float* __restrict__ xf, float* __restrict__ xb) {
    int mtile = blockIdx.x;
    int ntile = blockIdx.y;
    int tid = threadIdx.x;

    __shared__ float As[KC][LDP];
    __shared__ float Bs[KC][LDP];
    __shared__ int tok[MT];

    int g2base = ntile * NT;
    const bool fwd = (g2base < 1024);
    const float* Wih = fwd ? Wf_ih : Wb_ih;
    const float* bia = fwd ? bf_ih : bb_ih;
    const float* bib = fwd ? bf_hh : bb_hh;
    float* dst       = fwd ? xf    : xb;
    int glb = g2base & 1023;

    if (tid < MT) tok[tid] = sentence[(size_t)mtile * MT + tid];
    __syncthreads();

    float acc[8][8];
#pragma unroll
    for (int i = 0; i < 8; ++i)
#pragma unroll
        for (int jj = 0; jj < 8; ++jj) acc[i][jj] = 0.f;

    int m0 = (tid & 15) * 8;
    int n0 = (tid >> 4) * 8;
    int lr = tid >> 3;
    int lk = (tid & 7) * 4;

    for (int k0 = 0; k0 < EMB; k0 += KC) {
#pragma unroll
        for (int i = 0; i < 4; ++i) {
            int r = lr + 32 * i;
            float4 v = *(const float4*)(emb + (size_t)tok[r] * EMB + k0 + lk);
            As[lk + 0][r] = v.x; As[lk + 1][r] = v.y;
            As[lk + 2][r] = v.z; As[lk + 3][r] = v.w;
            float4 w = *(const float4*)(Wih + (size_t)(glb + r) * EMB + k0 + lk);
            Bs[lk + 0][r] = w.x; Bs[lk + 1][r] = w.y;
            Bs[lk + 2][r] = w.z; Bs[lk + 3][r] = w.w;
        }
        __syncthreads();
#pragma unroll
        for (int kk = 0; kk < KC; ++kk) {
            float4 a0 = *(const float4*)&As[kk][m0];
            float4 a1 = *(const float4*)&As[kk][m0 + 4];
            float4 b0 = *(const float4*)&Bs[kk][n0];
            float4 b1 = *(const float4*)&Bs[kk][n0 + 4];
            float av[8] = {a0.x, a0.y, a0.z, a0.w, a1.x, a1.y, a1.z, a1.w};
            float bv[8] = {b0.x, b0.y, b0.z, b0.w, b1.x, b1.y, b1.z, b1.w};
#pragma unroll
            for (int i = 0; i < 8; ++i)
#pragma unroll
                for (int jj = 0; jj < 8; ++jj) acc[i][jj] += av[i] * bv[jj];
        }
        __syncthreads();
    }

    float bs[8];
#pragma unroll
    for (int jj = 0; jj < 8; ++jj) {
        int gl = glb + n0 + jj;
        bs[jj] = bia[gl] + bib[gl];
    }
#pragma unroll
    for (int i = 0; i < 8; ++i) {
        size_t r = (size_t)mtile * MT + m0 + i;
        float4 s0 = {acc[i][0] + bs[0], acc[i][1] + bs[1],
                     acc[i][2] + bs[2], acc[i][3] + bs[3]};
        float4 s1 = {acc[i][4] + bs[4], acc[i][5] + bs[5],
                     acc[i][6] + bs[6], acc[i][7] + bs[7]};
        *(float4*)(dst + r * (size_t)G4 + glb + n0)     = s0;
        *(float4*)(dst + r * (size_t)G4 + glb + n0 + 4) = s1;
    }
}

// ---------------------------------------------------------------------------
// K2: cooperative LSTM scan v12 = v10 + LDS-pipe decongestion.
// Measured ladder: v5 1778 (2 bar, L2-W) -> v8 2008 (LDS-W; W-BW exonerated)
// -> v10 1690 (1 bar + x-prefetch) -> v11 3320 (wave-autonomous poll:
// REFUTED -- 4x LLC poll pressure, no shared discovery; reverted).
// v10 residual model: ~1.5us/step of per-CU LDS-pipe serialization (4 waves
// share one pipe: 32 h-reads + 16 W-reads + 4 writes + ~48 shfl_xor which
// compile to ds_swizzle = LDS pipe!) + ~0.5-1us exchange latency.
// v12 changes (both no-lose, bit-identical arithmetic):
//   1. red8(): DPP-based 8-lane reduce on the VALU pipe replaces shfl_xor.
//   2. Wreg[4][8]: ALL W register-staged from LDS. v8/v10 both showed
//      VGPR=132 -> the RA folded Wreg[4][4] back into in-loop ds_reads;
//      this retries at full width. If it folds again, fallback IS v10's
//      ds_read (VGPR counter is the discriminator).
// Protocol/barrier/publish identical to v10. No inline asm.
// ---------------------------------------------------------------------------
__global__ __launch_bounds__(256, 1) void lstm_scan12(
    const float* __restrict__ xf, const float* __restrict__ xb,
    const float* __restrict__ Wf_hh, const float* __restrict__ Wb_hh,
    float* __restrict__ hcat) {
    int blk = blockIdx.x;
    int grp = blk & 31;          // members of a group share blk%8 (XCD heur.)
    int s   = blk >> 5;          // J-slice 0..7
    int d   = grp >> 4;          // direction
    int gq  = grp & 15;          // batch quartet
    int b0  = gq * 4;
    int tid = threadIdx.x;
    int kseg = tid & 7;
    int j    = tid >> 3;
    int J    = s * 32 + j;
    int bown = kseg & 3;

    __shared__ f4 Wl[4][8][256];      // 128 KiB: per-thread private W slices
    __shared__ float hsL[2][4 * 288]; // double-buffered h stage (9 KiB)

    // --- stage W: 4 gate-rows of J, k-slice [kseg*32, +32) into LDS ---
    const float* Whh = d ? Wb_hh : Wf_hh;
#pragma unroll
    for (int g = 0; g < 4; ++g)
#pragma unroll
        for (int q = 0; q < 8; ++q)
            Wl[g][q][tid] =
                *(const f4*)(Whh + (size_t)(g * 256 + J) * 256 + kseg * 32 + q * 4);

    // --- register-stage ALL of W from own LDS slot (~128 VGPRs) ---
    f4 Wreg[4][8];
#pragma unroll
    for (int g = 0; g < 4; ++g)
#pragma unroll
        for (int q = 0; q < 8; ++q)
            Wreg[g][q] = Wl[g][q][tid];

    const float* x = d ? xb : xf;
    const float* xrow0 = x + (size_t)(b0 + bown) * TLEN * G4 + J;
    int sw = (tid >> 5) * 36 + (tid & 31);
    float c = 0.f;

    // prologue: x for the first step
    const float* xr0 = xrow0 + (size_t)(d ? (TLEN - 1) : 0) * G4;
    float xc0 = xr0[0], xc1 = xr0[256], xc2 = xr0[512], xc3 = xr0[768];

    for (int i = 0; i < TLEN; ++i) {
        int t = d ? (TLEN - 1 - i) : i;
        int buf = i & 1;

        if (i == 0) {
#pragma unroll
            for (int bb = 0; bb < 4; ++bb) hsL[0][bb * 288 + sw] = 0.f;
        } else {
            int tp = d ? (t + 1) : (t - 1);
            const unsigned* base = (const unsigned*)hcat +
                ((size_t)tp * BATCH + b0) * 512 + (size_t)d * HID + tid;
            unsigned u0, u1, u2, u3;
            for (;;) {
                u0 = ld_llc_u(base);
                u1 = ld_llc_u(base + 512);
                u2 = ld_llc_u(base + 1024);
                u3 = ld_llc_u(base + 1536);
                if (u0 != SENT && u1 != SENT && u2 != SENT && u3 != SENT) break;
                __builtin_amdgcn_s_sleep(1);
            }
            hsL[buf][0 * 288 + sw] = __uint_as_float(u0);
            hsL[buf][1 * 288 + sw] = __uint_as_float(u1);
            hsL[buf][2 * 288 + sw] = __uint_as_float(u2);
            hsL[buf][3 * 288 + sw] = __uint_as_float(u3);
        }
        __syncthreads();   // single barrier per step (stage -> compute)

        // --- prefetch x for the NEXT step (consumed a full step later) ---
        int tn = (i == TLEN - 1) ? t : (d ? (t - 1) : (t + 1));
        const float* xrn = xrow0 + (size_t)tn * G4;
        float xn0 = xrn[0], xn1 = xrn[256], xn2 = xrn[512], xn3 = xrn[768];

        // --- q-outer: read each h f4 once per bb, W from registers ---
        float a[4][4];               // [gate][bb], fully unrolled
#pragma unroll
        for (int g = 0; g < 4; ++g)
#pragma unroll
            for (int bb = 0; bb < 4; ++bb) a[g][bb] = 0.f;

        const float* hbase = hsL[buf] + kseg * 36;
#pragma unroll
        for (int q = 0; q < 8; ++q) {
            f4 w0 = Wreg[0][q];
            f4 w1 = Wreg[1][q];
            f4 w2 = Wreg[2][q];
            f4 w3 = Wreg[3][q];
#pragma unroll
            for (int bb = 0; bb < 4; ++bb) {
                f4 h4 = *(const f4*)(hbase + bb * 288 + q * 4);
                a[0][bb] += w0.x*h4.x + w0.y*h4.y + w0.z*h4.z + w0.w*h4.w;
                a[1][bb] += w1.x*h4.x + w1.y*h4.y + w1.z*h4.z + w1.w*h4.w;
                a[2][bb] += w2.x*h4.x + w2.y*h4.y + w2.z*h4.z + w2.w*h4.w;
                a[3][bb] += w3.x*h4.x + w3.y*h4.y + w3.z*h4.z + w3.w*h4.w;
            }
        }

        // --- reduce over the 8-lane kseg group: DPP on the VALU pipe ---
#pragma unroll
        for (int bb = 0; bb < 4; ++bb) {
            a[0][bb] = red8(a[0][bb]);
            a[1][bb] = red8(a[1][bb]);
            a[2][bb] = red8(a[2][bb]);
            a[3][bb] = red8(a[3][bb]);
        }

        // --- select own batch (constant-index ternary chain, no scratch) ---
        float A0 = bown == 0 ? a[0][0] : bown == 1 ? a[0][1] : bown == 2 ? a[0][2] : a[0][3];
        float A1 = bown == 0 ? a[1][0] : bown == 1 ? a[1][1] : bown == 2 ? a[1][2] : a[1][3];
        float A2 = bown == 0 ? a[2][0] : bown == 1 ? a[2][1] : bown == 2 ? a[2][2] : a[2][3];
        float A3 = bown == 0 ? a[3][0] : bown == 1 ? a[3][1] : bown == 2 ? a[3][2] : a[3][3];

        float ig = fsig(A0 + xc0);
        float fg = fsig(A1 + xc1);
        float gg = ftanh(A2 + xc2);
        float og = fsig(A3 + xc3);
        c = fg * c + ig * gg;
        float h = og * ftanh(c);
        if (kseg < 4)
            st_llc(hcat + ((size_t)t * BATCH + b0 + bown) * 512
                        + (size_t)d * HID + J, h);

        xc0 = xn0; xc1 = xn1; xc2 = xn2; xc3 = xn3;
        // no trailing barrier: hsL double-buffered; next stage writes buf^1,
        // and stage of THIS buf recurs only after the next barrier generation.
    }
}

// ---------------------------------------------------------------------------
// K3: feats[t,b,k] = hcat[t,b,:] . W_out[k,:] + b_out[k].
// ---------------------------------------------------------------------------
__global__ __launch_bounds__(256) void feats_kernel(
    const float* __restrict__ hcat, const float* __restrict__ Wout,
    const float* __restrict__ bout, float* __restrict__ feats) {
    int wid = threadIdx.x >> 6;
    int lane = threadIdx.x & 63;
    size_t row = (size_t)blockIdx.x * 4 + wid;
    const float* hrow = hcat + row * 512;
    float4 h0 = *(const float4*)(hrow + lane * 8);
    float4 h1 = *(const float4*)(hrow + lane * 8 + 4);
    for (int k2 = 0; k2 < KTAG; ++k2) {
        const float* wr = Wout + (size_t)k2 * 512 + lane * 8;
        float4 w0 = *(const float4*)wr;
        float4 w1 = *(const float4*)(wr + 4);
        float p = h0.x * w0.x + h0.y * w0.y + h0.z * w0.z + h0.w * w0.w
                + h1.x * w1.x + h1.y * w1.y + h1.z * w1.z + h1.w * w1.w;
#pragma unroll
        for (int off = 32; off; off >>= 1) p += __shfl_down(p, off);
        if (lane == 0) feats[row * KTAG + k2] = p + bout[k2];
    }
}

// ---------------------------------------------------------------------------
// K4: Viterbi DP + backtrace. One wave per batch. 8-step feats prefetch ring.
// ---------------------------------------------------------------------------
__global__ __launch_bounds__(64) void viterbi_kernel(
    const float* __restrict__ feats, const float* __restrict__ trans,
    const int* __restrict__ slen, float* __restrict__ out) {
    int b = blockIdx.x;
    int lane = threadIdx.x;
    __shared__ unsigned char bp[TLEN][KTAG];

    int len = slen[b];
    float tr[KTAG];
#pragma unroll
    for (int p = 0; p < KTAG; ++p) tr[p] = 0.f;
    if (lane < KTAG) {
#pragma unroll
        for (int p = 0; p < KTAG; ++p) tr[p] = trans[lane * KTAG + p];
    }
    float tstop = (lane < KTAG) ? trans[STOP_TAG * KTAG + lane] : NEGV;
    float dp = (lane == START_TAG) ? 0.f : NEGV;

    float fb[8];
#pragma unroll
    for (int k = 0; k < 8; ++k)
        fb[k] = (lane < KTAG) ? feats[((size_t)k * BATCH + b) * KTAG + lane] : 0.f;

    for (int t0 = 0; t0 < TLEN; t0 += 8) {
#pragma unroll
        for (int u = 0; u < 8; ++u) {
            int t = t0 + u;
            float ftc = fb[u];
            int tn = t + 8;
            fb[u] = (tn < TLEN && lane < KTAG)
                        ? feats[((size_t)tn * BATCH + b) * KTAG + lane] : 0.f;
            float best = -1e30f;
            int arg = 0;
#pragma unroll
            for (int p = 0; p < KTAG; ++p) {
                float dpp = __shfl(dp, p);
                float sc = dpp + tr[p];
                if (sc > best) { best = sc; arg = p; }
            }
            bool m = (t < len);
            if (lane < KTAG) {
                dp = m ? (best + ftc) : dp;
                bp[t][lane] = (unsigned char)(m ? arg : lane);
            }
        }
    }

    float term = dp + tstop;
    float bbest = -1e30f;
    int barg = 0;
#pragma unroll
    for (int p = 0; p < KTAG; ++p) {
        float v = __shfl(term, p);
        if (v > bbest) { bbest = v; barg = p; }
    }
    if (lane == 0) {
        out[b] = bbest;
        float* path = out + BATCH + (size_t)b * TLEN;
        int tag = barg;
        for (int t = TLEN - 1; t >= 0; --t) {
            path[t] = (float)tag;
            tag = bp[t][tag];
        }
    }
}

// ---------------------------------------------------------------------------
extern "C" void kernel_launch(void* const* d_in, const int* in_sizes, int n_in,
                              void* d_out, int out_size, void* d_ws, size_t ws_size,
                              hipStream_t stream) {
    const int*   sentence = (const int*)d_in[0];
    const int*   slen     = (const int*)d_in[1];
    const float* emb      = (const float*)d_in[2];
    const float* Wf_ih    = (const float*)d_in[3];
    const float* Wf_hh    = (const float*)d_in[4];
    const float* bf_ih    = (const float*)d_in[5];
    const float* bf_hh    = (const float*)d_in[6];
    const float* Wb_ih    = (const float*)d_in[7];
    const float* Wb_hh    = (const float*)d_in[8];
    const float* bb_ih    = (const float*)d_in[9];
    const float* bb_hh    = (const float*)d_in[10];
    const float* W_out    = (const float*)d_in[11];
    const float* b_out    = (const float*)d_in[12];
    const float* trans    = (const float*)d_in[13];
    float* out = (float*)d_out;

    char* ws = (char*)d_ws;
    float* xf    = (float*)(ws);                       // 134,217,728 B
    float* xb    = (float*)(ws + 134217728ull);        // 134,217,728 B
    float* hcat  = (float*)(ws + 268435456ull);        //  67,108,864 B
    float* feats = (float*)(ws + 335544320ull);        //   1,572,864 B

    // sentinel-fill hcat: 0xFFFFFFFF = -NaN, unreachable for tanh-bounded h
    hipMemsetAsync(hcat, 0xFF, 67108864ull, stream);
    hipLaunchKernelGGL(proj_kernel, dim3(256, 16), dim3(256), 0, stream,
                       sentence, emb, Wf_ih, Wb_ih, bf_ih, bf_hh, bb_ih, bb_hh, xf, xb);
    hipLaunchKernelGGL(lstm_scan12, dim3(256), dim3(256), 0, stream,
                       xf, xb, Wf_hh, Wb_hh, hcat);
    hipLaunchKernelGGL(feats_kernel, dim3(8192), dim3(256), 0, stream,
                       hcat, W_out, b_out, feats);
    hipLaunchKernelGGL(viterbi_kernel, dim3(64), dim3(64), 0, stream,
                       feats, trans, slen, out);
}